// Round 2
// baseline (3287.473 us; speedup 1.0000x reference)
//
#include <hip/hip_runtime.h>
#include <math.h>

// Color NGP, two-phase:
//   Phase A (encode): level-major grid; one thread per (point, level); 16 random
//     8B gathers per thread from one 4MB level slice -> L2-resident per XCD.
//     Writes enc as [L][P] float2 to workspace.
//   Phase B (MLP): one thread per point; 32->64->64->3 with exact GELU, weights
//     staged in LDS (uniform broadcast reads).
// Fallback: if ws_size is too small, use the round-1 fused kernel.

#define NLEV 16
#define TSIZE (1u << 19)
#define TMASK (TSIZE - 1u)

__device__ __forceinline__ float gelu_exact(float x) {
    return 0.5f * x * (1.0f + erff(x * 0.70710678118654752440f));
}

// ---------------- Phase A: hash-grid encode, level-major ----------------
__global__ __launch_bounds__(256, 6) void ngp_encode(
    const float* __restrict__ inputs,   // [B,N,3]
    const float* __restrict__ latent,   // [B,1]
    const float* __restrict__ table,    // [16, 2^19, 2]
    float2* __restrict__ enc,           // [L][P]
    int P, int bplShift, int nShift)
{
    const int bid = blockIdx.x;
    const int l = bid >> bplShift;                  // level = slow dimension
    const int p = ((bid & ((1 << bplShift) - 1)) << 8) + threadIdx.x;

    float x0 = inputs[p * 3 + 0];
    float x1 = inputs[p * 3 + 1];
    float x2 = inputs[p * 3 + 2];
    float x3 = latent[p >> nShift];
    x0 = (x0 + 1.0f) * 0.5f;
    x1 = (x1 + 1.0f) * 0.5f;
    x2 = (x2 + 1.0f) * 0.5f;
    x3 = (x3 + 1.0f) * 0.5f;

    const float LOG2S = (float)log2(1.3819);        // matches np.float32(np.log2(1.3819))
    const float s = exp2f((float)l * LOG2S) * 16.0f - 1.0f;

    const float px = fmaf(x0, s, 0.5f);
    const float py = fmaf(x1, s, 0.5f);
    const float pz = fmaf(x2, s, 0.5f);
    const float pw = fmaf(x3, s, 0.5f);
    const float fx = floorf(px), fy = floorf(py), fz = floorf(pz), fw = floorf(pw);
    const float rx = px - fx, ry = py - fy, rz = pz - fz, rw = pw - fw;

    const unsigned a0 = (unsigned)(int)fx;               const unsigned a1 = a0 + 1u;
    const unsigned b0 = (unsigned)(int)fy * 2654435761u; const unsigned b1v = b0 + 2654435761u;
    const unsigned c0 = (unsigned)(int)fz * 805459861u;  const unsigned c1 = c0 + 805459861u;
    const unsigned d0 = (unsigned)(int)fw * 3674653429u; const unsigned d1 = d0 + 3674653429u;

    const float wx0 = 1.0f - rx, wy0 = 1.0f - ry, wz0 = 1.0f - rz, ww0 = 1.0f - rw;
    const float wxy[4] = { wx0 * wy0, rx * wy0, wx0 * ry, rx * ry };
    const float wzw[4] = { wz0 * ww0, rz * ww0, wz0 * rw, rz * rw };

    const float2* __restrict__ tab2 = (const float2*)table;
    const unsigned base = (unsigned)l * TSIZE;

    float acc0 = 0.0f, acc1 = 0.0f;
    #pragma unroll
    for (int c = 0; c < 16; ++c) {
        unsigned h = ((c & 1) ? a1 : a0) ^ ((c & 2) ? b1v : b0)
                   ^ ((c & 4) ? c1 : c0) ^ ((c & 8) ? d1 : d0);
        const float2 v = tab2[base + (h & TMASK)];
        const float wgt = wxy[c & 3] * wzw[c >> 2];
        acc0 = fmaf(wgt, v.x, acc0);
        acc1 = fmaf(wgt, v.y, acc1);
    }
    enc[l * P + p] = make_float2(acc0, acc1);
}

// ---------------- Phase B: MLP 32->64->64->3 ----------------
__global__ __launch_bounds__(256, 4) void ngp_mlp(
    const float2* __restrict__ enc,     // [L][P]
    const float* __restrict__ W1, const float* __restrict__ b1,
    const float* __restrict__ W2, const float* __restrict__ b2,
    const float* __restrict__ W3, const float* __restrict__ b3,
    float* __restrict__ out, int P)
{
    __shared__ __align__(16) float sW1[2048];
    __shared__ __align__(16) float sW2[4096];
    __shared__ __align__(16) float sW3[192];
    __shared__ float sb1[64];
    __shared__ float sb2[64];
    __shared__ float sb3[4];

    const int tid = threadIdx.x;
    #pragma unroll
    for (int i = 0; i < 8; ++i)  sW1[tid + 256 * i] = W1[tid + 256 * i];
    #pragma unroll
    for (int i = 0; i < 16; ++i) sW2[tid + 256 * i] = W2[tid + 256 * i];
    if (tid < 192) sW3[tid] = W3[tid];
    if (tid < 64) { sb1[tid] = b1[tid]; sb2[tid] = b2[tid]; }
    if (tid < 3)  sb3[tid] = b3[tid];
    __syncthreads();

    const int p = blockIdx.x * 256 + tid;

    float h1[64];
    #pragma unroll
    for (int j = 0; j < 64; ++j) h1[j] = 0.0f;

    #pragma unroll 4
    for (int l = 0; l < NLEV; ++l) {
        const float2 e = enc[l * P + p];
        const float4* wr0 = (const float4*)&sW1[(2 * l    ) * 64];
        const float4* wr1 = (const float4*)&sW1[(2 * l + 1) * 64];
        #pragma unroll
        for (int j4 = 0; j4 < 16; ++j4) {
            const float4 wa = wr0[j4];
            const float4 wb = wr1[j4];
            h1[4 * j4 + 0] = fmaf(e.x, wa.x, fmaf(e.y, wb.x, h1[4 * j4 + 0]));
            h1[4 * j4 + 1] = fmaf(e.x, wa.y, fmaf(e.y, wb.y, h1[4 * j4 + 1]));
            h1[4 * j4 + 2] = fmaf(e.x, wa.z, fmaf(e.y, wb.z, h1[4 * j4 + 2]));
            h1[4 * j4 + 3] = fmaf(e.x, wa.w, fmaf(e.y, wb.w, h1[4 * j4 + 3]));
        }
    }

    #pragma unroll
    for (int j = 0; j < 64; ++j) h1[j] = gelu_exact(h1[j] + sb1[j]);

    float col0 = sb3[0], col1 = sb3[1], col2 = sb3[2];
    #pragma unroll 1
    for (int ch = 0; ch < 8; ++ch) {
        float acc[8];
        #pragma unroll
        for (int k = 0; k < 8; ++k) acc[k] = sb2[ch * 8 + k];
        #pragma unroll
        for (int i = 0; i < 64; ++i) {
            const float hv = h1[i];
            const float4* wr = (const float4*)&sW2[i * 64 + ch * 8];
            const float4 w0 = wr[0];
            const float4 w1 = wr[1];
            acc[0] = fmaf(hv, w0.x, acc[0]);
            acc[1] = fmaf(hv, w0.y, acc[1]);
            acc[2] = fmaf(hv, w0.z, acc[2]);
            acc[3] = fmaf(hv, w0.w, acc[3]);
            acc[4] = fmaf(hv, w1.x, acc[4]);
            acc[5] = fmaf(hv, w1.y, acc[5]);
            acc[6] = fmaf(hv, w1.z, acc[6]);
            acc[7] = fmaf(hv, w1.w, acc[7]);
        }
        #pragma unroll
        for (int k = 0; k < 8; ++k) {
            const float g = gelu_exact(acc[k]);
            const int j2 = ch * 8 + k;
            col0 = fmaf(g, sW3[j2 * 3 + 0], col0);
            col1 = fmaf(g, sW3[j2 * 3 + 1], col1);
            col2 = fmaf(g, sW3[j2 * 3 + 2], col2);
        }
    }

    out[p * 3 + 0] = col0;
    out[p * 3 + 1] = col1;
    out[p * 3 + 2] = col2;
}

// ---------------- Fallback: round-1 fused kernel (if ws too small) ----------------
__global__ __launch_bounds__(256) void ngp_fused(
    const float* __restrict__ inputs, const float* __restrict__ latent,
    const float* __restrict__ table,
    const float* __restrict__ W1, const float* __restrict__ b1,
    const float* __restrict__ W2, const float* __restrict__ b2,
    const float* __restrict__ W3, const float* __restrict__ b3,
    float* __restrict__ out)
{
    __shared__ __align__(16) float sW1[2048];
    __shared__ __align__(16) float sW2[4096];
    __shared__ __align__(16) float sW3[192];
    __shared__ float sb1[64];
    __shared__ float sb2[64];
    __shared__ float sb3[4];

    const int tid = threadIdx.x;
    #pragma unroll
    for (int i = 0; i < 8; ++i)  sW1[tid + 256 * i] = W1[tid + 256 * i];
    #pragma unroll
    for (int i = 0; i < 16; ++i) sW2[tid + 256 * i] = W2[tid + 256 * i];
    if (tid < 192) sW3[tid] = W3[tid];
    if (tid < 64) { sb1[tid] = b1[tid]; sb2[tid] = b2[tid]; }
    if (tid < 3)  sb3[tid] = b3[tid];

    const int p = blockIdx.x * 256 + tid;
    float x0 = inputs[p * 3 + 0];
    float x1 = inputs[p * 3 + 1];
    float x2 = inputs[p * 3 + 2];
    float x3 = latent[p >> 15];
    x0 = (x0 + 1.0f) * 0.5f; x1 = (x1 + 1.0f) * 0.5f;
    x2 = (x2 + 1.0f) * 0.5f; x3 = (x3 + 1.0f) * 0.5f;
    __syncthreads();

    float h1[64];
    #pragma unroll
    for (int j = 0; j < 64; ++j) h1[j] = 0.0f;

    const float LOG2S = (float)log2(1.3819);
    const float2* __restrict__ tab2 = (const float2*)table;

    #pragma unroll 2
    for (int l = 0; l < NLEV; ++l) {
        const float s = exp2f((float)l * LOG2S) * 16.0f - 1.0f;
        const float px = fmaf(x0, s, 0.5f);
        const float py = fmaf(x1, s, 0.5f);
        const float pz = fmaf(x2, s, 0.5f);
        const float pw = fmaf(x3, s, 0.5f);
        const float fx = floorf(px), fy = floorf(py), fz = floorf(pz), fw = floorf(pw);
        const float rx = px - fx, ry = py - fy, rz = pz - fz, rw = pw - fw;
        const unsigned a0 = (unsigned)(int)fx;               const unsigned a1 = a0 + 1u;
        const unsigned b0 = (unsigned)(int)fy * 2654435761u; const unsigned b1v = b0 + 2654435761u;
        const unsigned c0 = (unsigned)(int)fz * 805459861u;  const unsigned c1 = c0 + 805459861u;
        const unsigned d0 = (unsigned)(int)fw * 3674653429u; const unsigned d1 = d0 + 3674653429u;
        const float wx0 = 1.0f - rx, wy0 = 1.0f - ry, wz0 = 1.0f - rz, ww0 = 1.0f - rw;
        const float wxy[4] = { wx0 * wy0, rx * wy0, wx0 * ry, rx * ry };
        const float wzw[4] = { wz0 * ww0, rz * ww0, wz0 * rw, rz * rw };
        const unsigned base = (unsigned)l * TSIZE;
        float acc0 = 0.0f, acc1 = 0.0f;
        #pragma unroll
        for (int c = 0; c < 16; ++c) {
            unsigned h = ((c & 1) ? a1 : a0) ^ ((c & 2) ? b1v : b0)
                       ^ ((c & 4) ? c1 : c0) ^ ((c & 8) ? d1 : d0);
            const float2 v = tab2[base + (h & TMASK)];
            const float wgt = wxy[c & 3] * wzw[c >> 2];
            acc0 = fmaf(wgt, v.x, acc0);
            acc1 = fmaf(wgt, v.y, acc1);
        }
        const float4* wr0 = (const float4*)&sW1[(2 * l    ) * 64];
        const float4* wr1 = (const float4*)&sW1[(2 * l + 1) * 64];
        #pragma unroll
        for (int j4 = 0; j4 < 16; ++j4) {
            const float4 wa = wr0[j4];
            const float4 wb = wr1[j4];
            h1[4 * j4 + 0] = fmaf(acc0, wa.x, fmaf(acc1, wb.x, h1[4 * j4 + 0]));
            h1[4 * j4 + 1] = fmaf(acc0, wa.y, fmaf(acc1, wb.y, h1[4 * j4 + 1]));
            h1[4 * j4 + 2] = fmaf(acc0, wa.z, fmaf(acc1, wb.z, h1[4 * j4 + 2]));
            h1[4 * j4 + 3] = fmaf(acc0, wa.w, fmaf(acc1, wb.w, h1[4 * j4 + 3]));
        }
    }
    #pragma unroll
    for (int j = 0; j < 64; ++j) h1[j] = gelu_exact(h1[j] + sb1[j]);

    float col0 = sb3[0], col1 = sb3[1], col2 = sb3[2];
    #pragma unroll 1
    for (int ch = 0; ch < 8; ++ch) {
        float acc[8];
        #pragma unroll
        for (int k = 0; k < 8; ++k) acc[k] = sb2[ch * 8 + k];
        #pragma unroll
        for (int i = 0; i < 64; ++i) {
            const float hv = h1[i];
            const float4* wr = (const float4*)&sW2[i * 64 + ch * 8];
            const float4 w0 = wr[0];
            const float4 w1 = wr[1];
            acc[0] = fmaf(hv, w0.x, acc[0]);
            acc[1] = fmaf(hv, w0.y, acc[1]);
            acc[2] = fmaf(hv, w0.z, acc[2]);
            acc[3] = fmaf(hv, w0.w, acc[3]);
            acc[4] = fmaf(hv, w1.x, acc[4]);
            acc[5] = fmaf(hv, w1.y, acc[5]);
            acc[6] = fmaf(hv, w1.z, acc[6]);
            acc[7] = fmaf(hv, w1.w, acc[7]);
        }
        #pragma unroll
        for (int k = 0; k < 8; ++k) {
            const float g = gelu_exact(acc[k]);
            const int j2 = ch * 8 + k;
            col0 = fmaf(g, sW3[j2 * 3 + 0], col0);
            col1 = fmaf(g, sW3[j2 * 3 + 1], col1);
            col2 = fmaf(g, sW3[j2 * 3 + 2], col2);
        }
    }
    out[p * 3 + 0] = col0;
    out[p * 3 + 1] = col1;
    out[p * 3 + 2] = col2;
}

extern "C" void kernel_launch(void* const* d_in, const int* in_sizes, int n_in,
                              void* d_out, int out_size, void* d_ws, size_t ws_size,
                              hipStream_t stream) {
    const float* inputs = (const float*)d_in[0];
    const float* latent = (const float*)d_in[1];
    const float* table  = (const float*)d_in[2];
    const float* W1 = (const float*)d_in[3];
    const float* b1 = (const float*)d_in[4];
    const float* W2 = (const float*)d_in[5];
    const float* b2 = (const float*)d_in[6];
    const float* W3 = (const float*)d_in[7];
    const float* b3 = (const float*)d_in[8];
    float* out = (float*)d_out;

    const int P = in_sizes[0] / 3;              // 262144
    const int B = in_sizes[1];                  // 8
    const int N = P / B;                        // 32768
    const int nShift = 31 - __builtin_clz(N);   // 15
    const int bpl = P / 256;                    // 1024 blocks per level
    const int bplShift = 31 - __builtin_clz(bpl);

    const size_t encBytes = (size_t)P * NLEV * sizeof(float2);  // 33.5 MB

    if (ws_size >= encBytes && (P & 255) == 0 && (bpl & (bpl - 1)) == 0 && (N & (N - 1)) == 0) {
        float2* enc = (float2*)d_ws;
        ngp_encode<<<dim3(bpl * NLEV), dim3(256), 0, stream>>>(
            inputs, latent, table, enc, P, bplShift, nShift);
        ngp_mlp<<<dim3(P / 256), dim3(256), 0, stream>>>(
            enc, W1, b1, W2, b2, W3, b3, out, P);
    } else {
        ngp_fused<<<dim3(P / 256), dim3(256), 0, stream>>>(
            inputs, latent, table, W1, b1, W2, b2, W3, b3, out);
    }
}

// Round 3
// 598.652 us; speedup vs baseline: 5.4915x; 5.4915x over previous
//
#include <hip/hip_runtime.h>
#include <math.h>

// Color NGP, two-phase:
//   Phase A (encode): level-major grid; one thread per (point, level); 16 random
//     8B gathers per thread from one 4MB level slice -> L2-resident per XCD.
//     Writes enc as [L][P] float2 to workspace.
//   Phase B (MLP): one thread per point; 32->64->64->3 with exact GELU, weights
//     staged in LDS (uniform broadcast reads). NOTE: no min-waves clamp in
//     __launch_bounds__ -- round-2's (256,4) capped VGPR at 64 and spilled
//     h1[64] to scratch (10.7 GB of scratch traffic, 5.5x slowdown).
// Fallback: if ws_size is too small, use the round-1 fused kernel.

#define NLEV 16
#define TSIZE (1u << 19)
#define TMASK (TSIZE - 1u)

__device__ __forceinline__ float gelu_exact(float x) {
    return 0.5f * x * (1.0f + erff(x * 0.70710678118654752440f));
}

// ---------------- Phase A: hash-grid encode, level-major ----------------
__global__ __launch_bounds__(256, 6) void ngp_encode(
    const float* __restrict__ inputs,   // [B,N,3]
    const float* __restrict__ latent,   // [B,1]
    const float* __restrict__ table,    // [16, 2^19, 2]
    float2* __restrict__ enc,           // [L][P]
    int P, int bplShift, int nShift)
{
    const int bid = blockIdx.x;
    const int l = bid >> bplShift;                  // level = slow dimension
    const int p = ((bid & ((1 << bplShift) - 1)) << 8) + threadIdx.x;

    float x0 = inputs[p * 3 + 0];
    float x1 = inputs[p * 3 + 1];
    float x2 = inputs[p * 3 + 2];
    float x3 = latent[p >> nShift];
    x0 = (x0 + 1.0f) * 0.5f;
    x1 = (x1 + 1.0f) * 0.5f;
    x2 = (x2 + 1.0f) * 0.5f;
    x3 = (x3 + 1.0f) * 0.5f;

    const float LOG2S = (float)log2(1.3819);        // matches np.float32(np.log2(1.3819))
    const float s = exp2f((float)l * LOG2S) * 16.0f - 1.0f;

    const float px = fmaf(x0, s, 0.5f);
    const float py = fmaf(x1, s, 0.5f);
    const float pz = fmaf(x2, s, 0.5f);
    const float pw = fmaf(x3, s, 0.5f);
    const float fx = floorf(px), fy = floorf(py), fz = floorf(pz), fw = floorf(pw);
    const float rx = px - fx, ry = py - fy, rz = pz - fz, rw = pw - fw;

    const unsigned a0 = (unsigned)(int)fx;               const unsigned a1 = a0 + 1u;
    const unsigned b0 = (unsigned)(int)fy * 2654435761u; const unsigned b1v = b0 + 2654435761u;
    const unsigned c0 = (unsigned)(int)fz * 805459861u;  const unsigned c1 = c0 + 805459861u;
    const unsigned d0 = (unsigned)(int)fw * 3674653429u; const unsigned d1 = d0 + 3674653429u;

    const float wx0 = 1.0f - rx, wy0 = 1.0f - ry, wz0 = 1.0f - rz, ww0 = 1.0f - rw;
    const float wxy[4] = { wx0 * wy0, rx * wy0, wx0 * ry, rx * ry };
    const float wzw[4] = { wz0 * ww0, rz * ww0, wz0 * rw, rz * rw };

    const float2* __restrict__ tab2 = (const float2*)table;
    const unsigned base = (unsigned)l * TSIZE;

    float acc0 = 0.0f, acc1 = 0.0f;
    #pragma unroll
    for (int c = 0; c < 16; ++c) {
        unsigned h = ((c & 1) ? a1 : a0) ^ ((c & 2) ? b1v : b0)
                   ^ ((c & 4) ? c1 : c0) ^ ((c & 8) ? d1 : d0);
        const float2 v = tab2[base + (h & TMASK)];
        const float wgt = wxy[c & 3] * wzw[c >> 2];
        acc0 = fmaf(wgt, v.x, acc0);
        acc1 = fmaf(wgt, v.y, acc1);
    }
    enc[l * P + p] = make_float2(acc0, acc1);
}

// ---------------- Phase B: MLP 32->64->64->3 ----------------
__global__ __launch_bounds__(256) void ngp_mlp(
    const float2* __restrict__ enc,     // [L][P]
    const float* __restrict__ W1, const float* __restrict__ b1,
    const float* __restrict__ W2, const float* __restrict__ b2,
    const float* __restrict__ W3, const float* __restrict__ b3,
    float* __restrict__ out, int P)
{
    __shared__ __align__(16) float sW1[2048];
    __shared__ __align__(16) float sW2[4096];
    __shared__ __align__(16) float sW3[192];
    __shared__ float sb1[64];
    __shared__ float sb2[64];
    __shared__ float sb3[4];

    const int tid = threadIdx.x;
    #pragma unroll
    for (int i = 0; i < 8; ++i)  sW1[tid + 256 * i] = W1[tid + 256 * i];
    #pragma unroll
    for (int i = 0; i < 16; ++i) sW2[tid + 256 * i] = W2[tid + 256 * i];
    if (tid < 192) sW3[tid] = W3[tid];
    if (tid < 64) { sb1[tid] = b1[tid]; sb2[tid] = b2[tid]; }
    if (tid < 3)  sb3[tid] = b3[tid];
    __syncthreads();

    const int p = blockIdx.x * 256 + tid;

    float h1[64];
    #pragma unroll
    for (int j = 0; j < 64; ++j) h1[j] = 0.0f;

    #pragma unroll 4
    for (int l = 0; l < NLEV; ++l) {
        const float2 e = enc[l * P + p];
        const float4* wr0 = (const float4*)&sW1[(2 * l    ) * 64];
        const float4* wr1 = (const float4*)&sW1[(2 * l + 1) * 64];
        #pragma unroll
        for (int j4 = 0; j4 < 16; ++j4) {
            const float4 wa = wr0[j4];
            const float4 wb = wr1[j4];
            h1[4 * j4 + 0] = fmaf(e.x, wa.x, fmaf(e.y, wb.x, h1[4 * j4 + 0]));
            h1[4 * j4 + 1] = fmaf(e.x, wa.y, fmaf(e.y, wb.y, h1[4 * j4 + 1]));
            h1[4 * j4 + 2] = fmaf(e.x, wa.z, fmaf(e.y, wb.z, h1[4 * j4 + 2]));
            h1[4 * j4 + 3] = fmaf(e.x, wa.w, fmaf(e.y, wb.w, h1[4 * j4 + 3]));
        }
    }

    #pragma unroll
    for (int j = 0; j < 64; ++j) h1[j] = gelu_exact(h1[j] + sb1[j]);

    float col0 = sb3[0], col1 = sb3[1], col2 = sb3[2];
    #pragma unroll 1
    for (int ch = 0; ch < 8; ++ch) {
        float acc[8];
        #pragma unroll
        for (int k = 0; k < 8; ++k) acc[k] = sb2[ch * 8 + k];
        #pragma unroll
        for (int i = 0; i < 64; ++i) {
            const float hv = h1[i];
            const float4* wr = (const float4*)&sW2[i * 64 + ch * 8];
            const float4 w0 = wr[0];
            const float4 w1 = wr[1];
            acc[0] = fmaf(hv, w0.x, acc[0]);
            acc[1] = fmaf(hv, w0.y, acc[1]);
            acc[2] = fmaf(hv, w0.z, acc[2]);
            acc[3] = fmaf(hv, w0.w, acc[3]);
            acc[4] = fmaf(hv, w1.x, acc[4]);
            acc[5] = fmaf(hv, w1.y, acc[5]);
            acc[6] = fmaf(hv, w1.z, acc[6]);
            acc[7] = fmaf(hv, w1.w, acc[7]);
        }
        #pragma unroll
        for (int k = 0; k < 8; ++k) {
            const float g = gelu_exact(acc[k]);
            const int j2 = ch * 8 + k;
            col0 = fmaf(g, sW3[j2 * 3 + 0], col0);
            col1 = fmaf(g, sW3[j2 * 3 + 1], col1);
            col2 = fmaf(g, sW3[j2 * 3 + 2], col2);
        }
    }

    out[p * 3 + 0] = col0;
    out[p * 3 + 1] = col1;
    out[p * 3 + 2] = col2;
}

// ---------------- Fallback: round-1 fused kernel (if ws too small) ----------------
__global__ __launch_bounds__(256) void ngp_fused(
    const float* __restrict__ inputs, const float* __restrict__ latent,
    const float* __restrict__ table,
    const float* __restrict__ W1, const float* __restrict__ b1,
    const float* __restrict__ W2, const float* __restrict__ b2,
    const float* __restrict__ W3, const float* __restrict__ b3,
    float* __restrict__ out)
{
    __shared__ __align__(16) float sW1[2048];
    __shared__ __align__(16) float sW2[4096];
    __shared__ __align__(16) float sW3[192];
    __shared__ float sb1[64];
    __shared__ float sb2[64];
    __shared__ float sb3[4];

    const int tid = threadIdx.x;
    #pragma unroll
    for (int i = 0; i < 8; ++i)  sW1[tid + 256 * i] = W1[tid + 256 * i];
    #pragma unroll
    for (int i = 0; i < 16; ++i) sW2[tid + 256 * i] = W2[tid + 256 * i];
    if (tid < 192) sW3[tid] = W3[tid];
    if (tid < 64) { sb1[tid] = b1[tid]; sb2[tid] = b2[tid]; }
    if (tid < 3)  sb3[tid] = b3[tid];

    const int p = blockIdx.x * 256 + tid;
    float x0 = inputs[p * 3 + 0];
    float x1 = inputs[p * 3 + 1];
    float x2 = inputs[p * 3 + 2];
    float x3 = latent[p >> 15];
    x0 = (x0 + 1.0f) * 0.5f; x1 = (x1 + 1.0f) * 0.5f;
    x2 = (x2 + 1.0f) * 0.5f; x3 = (x3 + 1.0f) * 0.5f;
    __syncthreads();

    float h1[64];
    #pragma unroll
    for (int j = 0; j < 64; ++j) h1[j] = 0.0f;

    const float LOG2S = (float)log2(1.3819);
    const float2* __restrict__ tab2 = (const float2*)table;

    #pragma unroll 2
    for (int l = 0; l < NLEV; ++l) {
        const float s = exp2f((float)l * LOG2S) * 16.0f - 1.0f;
        const float px = fmaf(x0, s, 0.5f);
        const float py = fmaf(x1, s, 0.5f);
        const float pz = fmaf(x2, s, 0.5f);
        const float pw = fmaf(x3, s, 0.5f);
        const float fx = floorf(px), fy = floorf(py), fz = floorf(pz), fw = floorf(pw);
        const float rx = px - fx, ry = py - fy, rz = pz - fz, rw = pw - fw;
        const unsigned a0 = (unsigned)(int)fx;               const unsigned a1 = a0 + 1u;
        const unsigned b0 = (unsigned)(int)fy * 2654435761u; const unsigned b1v = b0 + 2654435761u;
        const unsigned c0 = (unsigned)(int)fz * 805459861u;  const unsigned c1 = c0 + 805459861u;
        const unsigned d0 = (unsigned)(int)fw * 3674653429u; const unsigned d1 = d0 + 3674653429u;
        const float wx0 = 1.0f - rx, wy0 = 1.0f - ry, wz0 = 1.0f - rz, ww0 = 1.0f - rw;
        const float wxy[4] = { wx0 * wy0, rx * wy0, wx0 * ry, rx * ry };
        const float wzw[4] = { wz0 * ww0, rz * ww0, wz0 * rw, rz * rw };
        const unsigned base = (unsigned)l * TSIZE;
        float acc0 = 0.0f, acc1 = 0.0f;
        #pragma unroll
        for (int c = 0; c < 16; ++c) {
            unsigned h = ((c & 1) ? a1 : a0) ^ ((c & 2) ? b1v : b0)
                       ^ ((c & 4) ? c1 : c0) ^ ((c & 8) ? d1 : d0);
            const float2 v = tab2[base + (h & TMASK)];
            const float wgt = wxy[c & 3] * wzw[c >> 2];
            acc0 = fmaf(wgt, v.x, acc0);
            acc1 = fmaf(wgt, v.y, acc1);
        }
        const float4* wr0 = (const float4*)&sW1[(2 * l    ) * 64];
        const float4* wr1 = (const float4*)&sW1[(2 * l + 1) * 64];
        #pragma unroll
        for (int j4 = 0; j4 < 16; ++j4) {
            const float4 wa = wr0[j4];
            const float4 wb = wr1[j4];
            h1[4 * j4 + 0] = fmaf(acc0, wa.x, fmaf(acc1, wb.x, h1[4 * j4 + 0]));
            h1[4 * j4 + 1] = fmaf(acc0, wa.y, fmaf(acc1, wb.y, h1[4 * j4 + 1]));
            h1[4 * j4 + 2] = fmaf(acc0, wa.z, fmaf(acc1, wb.z, h1[4 * j4 + 2]));
            h1[4 * j4 + 3] = fmaf(acc0, wa.w, fmaf(acc1, wb.w, h1[4 * j4 + 3]));
        }
    }
    #pragma unroll
    for (int j = 0; j < 64; ++j) h1[j] = gelu_exact(h1[j] + sb1[j]);

    float col0 = sb3[0], col1 = sb3[1], col2 = sb3[2];
    #pragma unroll 1
    for (int ch = 0; ch < 8; ++ch) {
        float acc[8];
        #pragma unroll
        for (int k = 0; k < 8; ++k) acc[k] = sb2[ch * 8 + k];
        #pragma unroll
        for (int i = 0; i < 64; ++i) {
            const float hv = h1[i];
            const float4* wr = (const float4*)&sW2[i * 64 + ch * 8];
            const float4 w0 = wr[0];
            const float4 w1 = wr[1];
            acc[0] = fmaf(hv, w0.x, acc[0]);
            acc[1] = fmaf(hv, w0.y, acc[1]);
            acc[2] = fmaf(hv, w0.z, acc[2]);
            acc[3] = fmaf(hv, w0.w, acc[3]);
            acc[4] = fmaf(hv, w1.x, acc[4]);
            acc[5] = fmaf(hv, w1.y, acc[5]);
            acc[6] = fmaf(hv, w1.z, acc[6]);
            acc[7] = fmaf(hv, w1.w, acc[7]);
        }
        #pragma unroll
        for (int k = 0; k < 8; ++k) {
            const float g = gelu_exact(acc[k]);
            const int j2 = ch * 8 + k;
            col0 = fmaf(g, sW3[j2 * 3 + 0], col0);
            col1 = fmaf(g, sW3[j2 * 3 + 1], col1);
            col2 = fmaf(g, sW3[j2 * 3 + 2], col2);
        }
    }
    out[p * 3 + 0] = col0;
    out[p * 3 + 1] = col1;
    out[p * 3 + 2] = col2;
}

extern "C" void kernel_launch(void* const* d_in, const int* in_sizes, int n_in,
                              void* d_out, int out_size, void* d_ws, size_t ws_size,
                              hipStream_t stream) {
    const float* inputs = (const float*)d_in[0];
    const float* latent = (const float*)d_in[1];
    const float* table  = (const float*)d_in[2];
    const float* W1 = (const float*)d_in[3];
    const float* b1 = (const float*)d_in[4];
    const float* W2 = (const float*)d_in[5];
    const float* b2 = (const float*)d_in[6];
    const float* W3 = (const float*)d_in[7];
    const float* b3 = (const float*)d_in[8];
    float* out = (float*)d_out;

    const int P = in_sizes[0] / 3;              // 262144
    const int B = in_sizes[1];                  // 8
    const int N = P / B;                        // 32768
    const int nShift = 31 - __builtin_clz(N);   // 15
    const int bpl = P / 256;                    // 1024 blocks per level
    const int bplShift = 31 - __builtin_clz(bpl);

    const size_t encBytes = (size_t)P * NLEV * sizeof(float2);  // 33.5 MB

    if (ws_size >= encBytes && (P & 255) == 0 && (bpl & (bpl - 1)) == 0 && (N & (N - 1)) == 0) {
        float2* enc = (float2*)d_ws;
        ngp_encode<<<dim3(bpl * NLEV), dim3(256), 0, stream>>>(
            inputs, latent, table, enc, P, bplShift, nShift);
        ngp_mlp<<<dim3(P / 256), dim3(256), 0, stream>>>(
            enc, W1, b1, W2, b2, W3, b3, out, P);
    } else {
        ngp_fused<<<dim3(P / 256), dim3(256), 0, stream>>>(
            inputs, latent, table, W1, b1, W2, b2, W3, b3, out);
    }
}

// Round 4
// 541.609 us; speedup vs baseline: 6.0698x; 1.1053x over previous
//
#include <hip/hip_runtime.h>
#include <math.h>

// Color NGP, two-phase:
//   Phase A (encode): level-major grid; one thread per (point, level); 16 random
//     8B gathers per thread from one 4MB level slice -> L2-resident per XCD.
//     Writes enc as [L][P] float2 to workspace.  (~190 us, near L2 gather bound)
//   Phase B (MLP): one thread per point; 32->64->64->3, exact GELU.
//     Weights read via wave-UNIFORM indices directly from global -> compiler
//     emits s_load into SGPRs (v_fma takes 1 SGPR operand). No LDS staging,
//     no float4 VGPR temps. Round-3 lesson: LDS-staged float4 weights + full
//     unroll spilled h1[64] (240 MB scratch writes, 405 us).
// Fallback: if ws_size is too small, use the fused single-kernel path.

#define NLEV 16
#define TSIZE (1u << 19)
#define TMASK (TSIZE - 1u)

__device__ __forceinline__ float gelu_exact(float x) {
    return 0.5f * x * (1.0f + erff(x * 0.70710678118654752440f));
}

// ---------------- Phase A: hash-grid encode, level-major ----------------
__global__ __launch_bounds__(256, 6) void ngp_encode(
    const float* __restrict__ inputs,   // [B,N,3]
    const float* __restrict__ latent,   // [B,1]
    const float* __restrict__ table,    // [16, 2^19, 2]
    float2* __restrict__ enc,           // [L][P]
    int P, int bplShift, int nShift)
{
    const int bid = blockIdx.x;
    const int l = bid >> bplShift;                  // level = slow dimension
    const int p = ((bid & ((1 << bplShift) - 1)) << 8) + threadIdx.x;

    float x0 = inputs[p * 3 + 0];
    float x1 = inputs[p * 3 + 1];
    float x2 = inputs[p * 3 + 2];
    float x3 = latent[p >> nShift];
    x0 = (x0 + 1.0f) * 0.5f;
    x1 = (x1 + 1.0f) * 0.5f;
    x2 = (x2 + 1.0f) * 0.5f;
    x3 = (x3 + 1.0f) * 0.5f;

    const float LOG2S = (float)log2(1.3819);        // matches np.float32(np.log2(1.3819))
    const float s = exp2f((float)l * LOG2S) * 16.0f - 1.0f;

    const float px = fmaf(x0, s, 0.5f);
    const float py = fmaf(x1, s, 0.5f);
    const float pz = fmaf(x2, s, 0.5f);
    const float pw = fmaf(x3, s, 0.5f);
    const float fx = floorf(px), fy = floorf(py), fz = floorf(pz), fw = floorf(pw);
    const float rx = px - fx, ry = py - fy, rz = pz - fz, rw = pw - fw;

    const unsigned a0 = (unsigned)(int)fx;               const unsigned a1 = a0 + 1u;
    const unsigned b0 = (unsigned)(int)fy * 2654435761u; const unsigned b1v = b0 + 2654435761u;
    const unsigned c0 = (unsigned)(int)fz * 805459861u;  const unsigned c1 = c0 + 805459861u;
    const unsigned d0 = (unsigned)(int)fw * 3674653429u; const unsigned d1 = d0 + 3674653429u;

    const float wx0 = 1.0f - rx, wy0 = 1.0f - ry, wz0 = 1.0f - rz, ww0 = 1.0f - rw;
    const float wxy[4] = { wx0 * wy0, rx * wy0, wx0 * ry, rx * ry };
    const float wzw[4] = { wz0 * ww0, rz * ww0, wz0 * rw, rz * rw };

    const float2* __restrict__ tab2 = (const float2*)table;
    const unsigned base = (unsigned)l * TSIZE;

    float acc0 = 0.0f, acc1 = 0.0f;
    #pragma unroll
    for (int c = 0; c < 16; ++c) {
        unsigned h = ((c & 1) ? a1 : a0) ^ ((c & 2) ? b1v : b0)
                   ^ ((c & 4) ? c1 : c0) ^ ((c & 8) ? d1 : d0);
        const float2 v = tab2[base + (h & TMASK)];
        const float wgt = wxy[c & 3] * wzw[c >> 2];
        acc0 = fmaf(wgt, v.x, acc0);
        acc1 = fmaf(wgt, v.y, acc1);
    }
    enc[l * P + p] = make_float2(acc0, acc1);
}

// ---------------- Phase B: MLP 32->64->64->3, scalar weight loads ----------------
__global__ __launch_bounds__(256) void ngp_mlp(
    const float2* __restrict__ enc,     // [L][P]
    const float* __restrict__ W1, const float* __restrict__ b1,
    const float* __restrict__ W2, const float* __restrict__ b2,
    const float* __restrict__ W3, const float* __restrict__ b3,
    float* __restrict__ out, int P)
{
    const int p = blockIdx.x * 256 + threadIdx.x;

    float h1[64];
    #pragma unroll
    for (int j = 0; j < 64; ++j) h1[j] = 0.0f;

    // Layer 1: h1 += e.x * W1[2l,:] + e.y * W1[2l+1,:]  (weights wave-uniform)
    #pragma unroll 2
    for (int l = 0; l < NLEV; ++l) {
        const float2 e = enc[l * P + p];
        const float* __restrict__ w0 = W1 + (2 * l) * 64;
        const float* __restrict__ w1 = W1 + (2 * l + 1) * 64;
        #pragma unroll
        for (int j = 0; j < 64; ++j) {
            h1[j] = fmaf(e.x, w0[j], fmaf(e.y, w1[j], h1[j]));
        }
    }

    // Bias + exact GELU
    #pragma unroll 8
    for (int j = 0; j < 64; ++j) h1[j] = gelu_exact(h1[j] + b1[j]);

    // Layer 2 (64->64) in chunks of 8 outputs, fused with layer 3 (64->3)
    float col0 = b3[0], col1 = b3[1], col2 = b3[2];
    #pragma unroll 1
    for (int ch = 0; ch < 8; ++ch) {
        float acc[8];
        #pragma unroll
        for (int k = 0; k < 8; ++k) acc[k] = b2[ch * 8 + k];
        #pragma unroll 8
        for (int i = 0; i < 64; ++i) {
            const float hv = h1[i];
            const float* __restrict__ wr = W2 + i * 64 + ch * 8;
            #pragma unroll
            for (int k = 0; k < 8; ++k) acc[k] = fmaf(hv, wr[k], acc[k]);
        }
        #pragma unroll
        for (int k = 0; k < 8; ++k) {
            const float g = gelu_exact(acc[k]);
            const int j2 = ch * 8 + k;
            col0 = fmaf(g, W3[j2 * 3 + 0], col0);
            col1 = fmaf(g, W3[j2 * 3 + 1], col1);
            col2 = fmaf(g, W3[j2 * 3 + 2], col2);
        }
    }

    out[p * 3 + 0] = col0;
    out[p * 3 + 1] = col1;
    out[p * 3 + 2] = col2;
}

// ---------------- Fallback: fused single kernel (if ws too small) ----------------
__global__ __launch_bounds__(256) void ngp_fused(
    const float* __restrict__ inputs, const float* __restrict__ latent,
    const float* __restrict__ table,
    const float* __restrict__ W1, const float* __restrict__ b1,
    const float* __restrict__ W2, const float* __restrict__ b2,
    const float* __restrict__ W3, const float* __restrict__ b3,
    float* __restrict__ out)
{
    const int p = blockIdx.x * 256 + threadIdx.x;
    float x0 = inputs[p * 3 + 0];
    float x1 = inputs[p * 3 + 1];
    float x2 = inputs[p * 3 + 2];
    float x3 = latent[p >> 15];
    x0 = (x0 + 1.0f) * 0.5f; x1 = (x1 + 1.0f) * 0.5f;
    x2 = (x2 + 1.0f) * 0.5f; x3 = (x3 + 1.0f) * 0.5f;

    float h1[64];
    #pragma unroll
    for (int j = 0; j < 64; ++j) h1[j] = 0.0f;

    const float LOG2S = (float)log2(1.3819);
    const float2* __restrict__ tab2 = (const float2*)table;

    #pragma unroll 2
    for (int l = 0; l < NLEV; ++l) {
        const float s = exp2f((float)l * LOG2S) * 16.0f - 1.0f;
        const float px = fmaf(x0, s, 0.5f);
        const float py = fmaf(x1, s, 0.5f);
        const float pz = fmaf(x2, s, 0.5f);
        const float pw = fmaf(x3, s, 0.5f);
        const float fx = floorf(px), fy = floorf(py), fz = floorf(pz), fw = floorf(pw);
        const float rx = px - fx, ry = py - fy, rz = pz - fz, rw = pw - fw;
        const unsigned a0 = (unsigned)(int)fx;               const unsigned a1 = a0 + 1u;
        const unsigned b0 = (unsigned)(int)fy * 2654435761u; const unsigned b1v = b0 + 2654435761u;
        const unsigned c0 = (unsigned)(int)fz * 805459861u;  const unsigned c1 = c0 + 805459861u;
        const unsigned d0 = (unsigned)(int)fw * 3674653429u; const unsigned d1 = d0 + 3674653429u;
        const float wx0 = 1.0f - rx, wy0 = 1.0f - ry, wz0 = 1.0f - rz, ww0 = 1.0f - rw;
        const float wxy[4] = { wx0 * wy0, rx * wy0, wx0 * ry, rx * ry };
        const float wzw[4] = { wz0 * ww0, rz * ww0, wz0 * rw, rz * rw };
        const unsigned base = (unsigned)l * TSIZE;
        float acc0 = 0.0f, acc1 = 0.0f;
        #pragma unroll
        for (int c = 0; c < 16; ++c) {
            unsigned h = ((c & 1) ? a1 : a0) ^ ((c & 2) ? b1v : b0)
                       ^ ((c & 4) ? c1 : c0) ^ ((c & 8) ? d1 : d0);
            const float2 v = tab2[base + (h & TMASK)];
            const float wgt = wxy[c & 3] * wzw[c >> 2];
            acc0 = fmaf(wgt, v.x, acc0);
            acc1 = fmaf(wgt, v.y, acc1);
        }
        const float* __restrict__ w0 = W1 + (2 * l) * 64;
        const float* __restrict__ w1 = W1 + (2 * l + 1) * 64;
        #pragma unroll
        for (int j = 0; j < 64; ++j) {
            h1[j] = fmaf(acc0, w0[j], fmaf(acc1, w1[j], h1[j]));
        }
    }
    #pragma unroll 8
    for (int j = 0; j < 64; ++j) h1[j] = gelu_exact(h1[j] + b1[j]);

    float col0 = b3[0], col1 = b3[1], col2 = b3[2];
    #pragma unroll 1
    for (int ch = 0; ch < 8; ++ch) {
        float acc[8];
        #pragma unroll
        for (int k = 0; k < 8; ++k) acc[k] = b2[ch * 8 + k];
        #pragma unroll 8
        for (int i = 0; i < 64; ++i) {
            const float hv = h1[i];
            const float* __restrict__ wr = W2 + i * 64 + ch * 8;
            #pragma unroll
            for (int k = 0; k < 8; ++k) acc[k] = fmaf(hv, wr[k], acc[k]);
        }
        #pragma unroll
        for (int k = 0; k < 8; ++k) {
            const float g = gelu_exact(acc[k]);
            const int j2 = ch * 8 + k;
            col0 = fmaf(g, W3[j2 * 3 + 0], col0);
            col1 = fmaf(g, W3[j2 * 3 + 1], col1);
            col2 = fmaf(g, W3[j2 * 3 + 2], col2);
        }
    }
    out[p * 3 + 0] = col0;
    out[p * 3 + 1] = col1;
    out[p * 3 + 2] = col2;
}

extern "C" void kernel_launch(void* const* d_in, const int* in_sizes, int n_in,
                              void* d_out, int out_size, void* d_ws, size_t ws_size,
                              hipStream_t stream) {
    const float* inputs = (const float*)d_in[0];
    const float* latent = (const float*)d_in[1];
    const float* table  = (const float*)d_in[2];
    const float* W1 = (const float*)d_in[3];
    const float* b1 = (const float*)d_in[4];
    const float* W2 = (const float*)d_in[5];
    const float* b2 = (const float*)d_in[6];
    const float* W3 = (const float*)d_in[7];
    const float* b3 = (const float*)d_in[8];
    float* out = (float*)d_out;

    const int P = in_sizes[0] / 3;              // 262144
    const int B = in_sizes[1];                  // 8
    const int N = P / B;                        // 32768
    const int nShift = 31 - __builtin_clz(N);   // 15
    const int bpl = P / 256;                    // 1024 blocks per level
    const int bplShift = 31 - __builtin_clz(bpl);

    const size_t encBytes = (size_t)P * NLEV * sizeof(float2);  // 33.5 MB

    if (ws_size >= encBytes && (P & 255) == 0 && (bpl & (bpl - 1)) == 0 && (N & (N - 1)) == 0) {
        float2* enc = (float2*)d_ws;
        ngp_encode<<<dim3(bpl * NLEV), dim3(256), 0, stream>>>(
            inputs, latent, table, enc, P, bplShift, nShift);
        ngp_mlp<<<dim3(P / 256), dim3(256), 0, stream>>>(
            enc, W1, b1, W2, b2, W3, b3, out, P);
    } else {
        ngp_fused<<<dim3(P / 256), dim3(256), 0, stream>>>(
            inputs, latent, table, W1, b1, W2, b2, W3, b3, out);
    }
}

// Round 5
// 506.288 us; speedup vs baseline: 6.4933x; 1.0698x over previous
//
#include <hip/hip_runtime.h>
#include <math.h>

// Color NGP, two-phase:
//   Phase A (encode): level-major grid; one thread per (point, level); 16 random
//     8B gathers per thread from one 4MB level slice -> L2-resident per XCD.
//     Writes enc as [L][P] float2 to workspace.  (~180 us)
//   Phase B (MLP): one thread per point; 32->64->64->3, exact GELU.
//     Weights read via wave-UNIFORM indices directly from global -> s_load into
//     SGPRs; v_fma takes the SGPR operand. CRITICAL (round-4 lesson, rule #20):
//     h1[64] must ONLY be indexed with compile-time constants -- a partial
//     unroll (#pragma unroll 8) left runtime indices and the compiler put h1
//     in scratch (1.5 GB of scratch traffic, 361 us). Full unroll everywhere.
// Fallback: if ws_size is too small, use the fused single-kernel path.

#define NLEV 16
#define TSIZE (1u << 19)
#define TMASK (TSIZE - 1u)

__device__ __forceinline__ float gelu_exact(float x) {
    return 0.5f * x * (1.0f + erff(x * 0.70710678118654752440f));
}

// ---------------- Phase A: hash-grid encode, level-major ----------------
__global__ __launch_bounds__(256, 6) void ngp_encode(
    const float* __restrict__ inputs,   // [B,N,3]
    const float* __restrict__ latent,   // [B,1]
    const float* __restrict__ table,    // [16, 2^19, 2]
    float2* __restrict__ enc,           // [L][P]
    int P, int bplShift, int nShift)
{
    const int bid = blockIdx.x;
    const int l = bid >> bplShift;                  // level = slow dimension
    const int p = ((bid & ((1 << bplShift) - 1)) << 8) + threadIdx.x;

    float x0 = inputs[p * 3 + 0];
    float x1 = inputs[p * 3 + 1];
    float x2 = inputs[p * 3 + 2];
    float x3 = latent[p >> nShift];
    x0 = (x0 + 1.0f) * 0.5f;
    x1 = (x1 + 1.0f) * 0.5f;
    x2 = (x2 + 1.0f) * 0.5f;
    x3 = (x3 + 1.0f) * 0.5f;

    const float LOG2S = (float)log2(1.3819);        // matches np.float32(np.log2(1.3819))
    const float s = exp2f((float)l * LOG2S) * 16.0f - 1.0f;

    const float px = fmaf(x0, s, 0.5f);
    const float py = fmaf(x1, s, 0.5f);
    const float pz = fmaf(x2, s, 0.5f);
    const float pw = fmaf(x3, s, 0.5f);
    const float fx = floorf(px), fy = floorf(py), fz = floorf(pz), fw = floorf(pw);
    const float rx = px - fx, ry = py - fy, rz = pz - fz, rw = pw - fw;

    const unsigned a0 = (unsigned)(int)fx;               const unsigned a1 = a0 + 1u;
    const unsigned b0 = (unsigned)(int)fy * 2654435761u; const unsigned b1v = b0 + 2654435761u;
    const unsigned c0 = (unsigned)(int)fz * 805459861u;  const unsigned c1 = c0 + 805459861u;
    const unsigned d0 = (unsigned)(int)fw * 3674653429u; const unsigned d1 = d0 + 3674653429u;

    const float wx0 = 1.0f - rx, wy0 = 1.0f - ry, wz0 = 1.0f - rz, ww0 = 1.0f - rw;
    const float wxy[4] = { wx0 * wy0, rx * wy0, wx0 * ry, rx * ry };
    const float wzw[4] = { wz0 * ww0, rz * ww0, wz0 * rw, rz * rw };

    const float2* __restrict__ tab2 = (const float2*)table;
    const unsigned base = (unsigned)l * TSIZE;

    float acc0 = 0.0f, acc1 = 0.0f;
    #pragma unroll
    for (int c = 0; c < 16; ++c) {
        unsigned h = ((c & 1) ? a1 : a0) ^ ((c & 2) ? b1v : b0)
                   ^ ((c & 4) ? c1 : c0) ^ ((c & 8) ? d1 : d0);
        const float2 v = tab2[base + (h & TMASK)];
        const float wgt = wxy[c & 3] * wzw[c >> 2];
        acc0 = fmaf(wgt, v.x, acc0);
        acc1 = fmaf(wgt, v.y, acc1);
    }
    enc[l * P + p] = make_float2(acc0, acc1);
}

// ---------------- Phase B: MLP 32->64->64->3, scalar weight loads ----------------
__global__ __launch_bounds__(256) void ngp_mlp(
    const float2* __restrict__ enc,     // [L][P]
    const float* __restrict__ W1, const float* __restrict__ b1,
    const float* __restrict__ W2, const float* __restrict__ b2,
    const float* __restrict__ W3, const float* __restrict__ b3,
    float* __restrict__ out, int P)
{
    const int p = blockIdx.x * 256 + threadIdx.x;

    float h1[64];
    #pragma unroll
    for (int j = 0; j < 64; ++j) h1[j] = 0.0f;

    // Layer 1: h1 += e.x * W1[2l,:] + e.y * W1[2l+1,:]  (weights wave-uniform)
    #pragma unroll 2
    for (int l = 0; l < NLEV; ++l) {
        const float2 e = enc[l * P + p];
        const float* __restrict__ w0 = W1 + (2 * l) * 64;
        const float* __restrict__ w1 = W1 + (2 * l + 1) * 64;
        #pragma unroll
        for (int j = 0; j < 64; ++j) {
            h1[j] = fmaf(e.x, w0[j], fmaf(e.y, w1[j], h1[j]));
        }
    }

    // Bias + exact GELU (FULL unroll: h1 index must be compile-time)
    #pragma unroll
    for (int j = 0; j < 64; ++j) h1[j] = gelu_exact(h1[j] + b1[j]);

    // Layer 2 (64->64) in chunks of 8 outputs, fused with layer 3 (64->3)
    float col0 = b3[0], col1 = b3[1], col2 = b3[2];
    #pragma unroll 1
    for (int ch = 0; ch < 8; ++ch) {
        float acc[8];
        #pragma unroll
        for (int k = 0; k < 8; ++k) acc[k] = b2[ch * 8 + k];
        // FULL unroll: h1[i] index must be compile-time (rule #20)
        #pragma unroll
        for (int i = 0; i < 64; ++i) {
            const float hv = h1[i];
            const float* __restrict__ wr = W2 + i * 64 + ch * 8;
            #pragma unroll
            for (int k = 0; k < 8; ++k) acc[k] = fmaf(hv, wr[k], acc[k]);
        }
        #pragma unroll
        for (int k = 0; k < 8; ++k) {
            const float g = gelu_exact(acc[k]);
            const int j2 = ch * 8 + k;
            col0 = fmaf(g, W3[j2 * 3 + 0], col0);
            col1 = fmaf(g, W3[j2 * 3 + 1], col1);
            col2 = fmaf(g, W3[j2 * 3 + 2], col2);
        }
    }

    out[p * 3 + 0] = col0;
    out[p * 3 + 1] = col1;
    out[p * 3 + 2] = col2;
}

// ---------------- Fallback: fused single kernel (if ws too small) ----------------
__global__ __launch_bounds__(256) void ngp_fused(
    const float* __restrict__ inputs, const float* __restrict__ latent,
    const float* __restrict__ table,
    const float* __restrict__ W1, const float* __restrict__ b1,
    const float* __restrict__ W2, const float* __restrict__ b2,
    const float* __restrict__ W3, const float* __restrict__ b3,
    float* __restrict__ out)
{
    const int p = blockIdx.x * 256 + threadIdx.x;
    float x0 = inputs[p * 3 + 0];
    float x1 = inputs[p * 3 + 1];
    float x2 = inputs[p * 3 + 2];
    float x3 = latent[p >> 15];
    x0 = (x0 + 1.0f) * 0.5f; x1 = (x1 + 1.0f) * 0.5f;
    x2 = (x2 + 1.0f) * 0.5f; x3 = (x3 + 1.0f) * 0.5f;

    float h1[64];
    #pragma unroll
    for (int j = 0; j < 64; ++j) h1[j] = 0.0f;

    const float LOG2S = (float)log2(1.3819);
    const float2* __restrict__ tab2 = (const float2*)table;

    #pragma unroll 2
    for (int l = 0; l < NLEV; ++l) {
        const float s = exp2f((float)l * LOG2S) * 16.0f - 1.0f;
        const float px = fmaf(x0, s, 0.5f);
        const float py = fmaf(x1, s, 0.5f);
        const float pz = fmaf(x2, s, 0.5f);
        const float pw = fmaf(x3, s, 0.5f);
        const float fx = floorf(px), fy = floorf(py), fz = floorf(pz), fw = floorf(pw);
        const float rx = px - fx, ry = py - fy, rz = pz - fz, rw = pw - fw;
        const unsigned a0 = (unsigned)(int)fx;               const unsigned a1 = a0 + 1u;
        const unsigned b0 = (unsigned)(int)fy * 2654435761u; const unsigned b1v = b0 + 2654435761u;
        const unsigned c0 = (unsigned)(int)fz * 805459861u;  const unsigned c1 = c0 + 805459861u;
        const unsigned d0 = (unsigned)(int)fw * 3674653429u; const unsigned d1 = d0 + 3674653429u;
        const float wx0 = 1.0f - rx, wy0 = 1.0f - ry, wz0 = 1.0f - rz, ww0 = 1.0f - rw;
        const float wxy[4] = { wx0 * wy0, rx * wy0, wx0 * ry, rx * ry };
        const float wzw[4] = { wz0 * ww0, rz * ww0, wz0 * rw, rz * rw };
        const unsigned base = (unsigned)l * TSIZE;
        float acc0 = 0.0f, acc1 = 0.0f;
        #pragma unroll
        for (int c = 0; c < 16; ++c) {
            unsigned h = ((c & 1) ? a1 : a0) ^ ((c & 2) ? b1v : b0)
                       ^ ((c & 4) ? c1 : c0) ^ ((c & 8) ? d1 : d0);
            const float2 v = tab2[base + (h & TMASK)];
            const float wgt = wxy[c & 3] * wzw[c >> 2];
            acc0 = fmaf(wgt, v.x, acc0);
            acc1 = fmaf(wgt, v.y, acc1);
        }
        const float* __restrict__ w0 = W1 + (2 * l) * 64;
        const float* __restrict__ w1 = W1 + (2 * l + 1) * 64;
        #pragma unroll
        for (int j = 0; j < 64; ++j) {
            h1[j] = fmaf(acc0, w0[j], fmaf(acc1, w1[j], h1[j]));
        }
    }
    #pragma unroll
    for (int j = 0; j < 64; ++j) h1[j] = gelu_exact(h1[j] + b1[j]);

    float col0 = b3[0], col1 = b3[1], col2 = b3[2];
    #pragma unroll 1
    for (int ch = 0; ch < 8; ++ch) {
        float acc[8];
        #pragma unroll
        for (int k = 0; k < 8; ++k) acc[k] = b2[ch * 8 + k];
        #pragma unroll
        for (int i = 0; i < 64; ++i) {
            const float hv = h1[i];
            const float* __restrict__ wr = W2 + i * 64 + ch * 8;
            #pragma unroll
            for (int k = 0; k < 8; ++k) acc[k] = fmaf(hv, wr[k], acc[k]);
        }
        #pragma unroll
        for (int k = 0; k < 8; ++k) {
            const float g = gelu_exact(acc[k]);
            const int j2 = ch * 8 + k;
            col0 = fmaf(g, W3[j2 * 3 + 0], col0);
            col1 = fmaf(g, W3[j2 * 3 + 1], col1);
            col2 = fmaf(g, W3[j2 * 3 + 2], col2);
        }
    }
    out[p * 3 + 0] = col0;
    out[p * 3 + 1] = col1;
    out[p * 3 + 2] = col2;
}

extern "C" void kernel_launch(void* const* d_in, const int* in_sizes, int n_in,
                              void* d_out, int out_size, void* d_ws, size_t ws_size,
                              hipStream_t stream) {
    const float* inputs = (const float*)d_in[0];
    const float* latent = (const float*)d_in[1];
    const float* table  = (const float*)d_in[2];
    const float* W1 = (const float*)d_in[3];
    const float* b1 = (const float*)d_in[4];
    const float* W2 = (const float*)d_in[5];
    const float* b2 = (const float*)d_in[6];
    const float* W3 = (const float*)d_in[7];
    const float* b3 = (const float*)d_in[8];
    float* out = (float*)d_out;

    const int P = in_sizes[0] / 3;              // 262144
    const int B = in_sizes[1];                  // 8
    const int N = P / B;                        // 32768
    const int nShift = 31 - __builtin_clz(N);   // 15
    const int bpl = P / 256;                    // 1024 blocks per level
    const int bplShift = 31 - __builtin_clz(bpl);

    const size_t encBytes = (size_t)P * NLEV * sizeof(float2);  // 33.5 MB

    if (ws_size >= encBytes && (P & 255) == 0 && (bpl & (bpl - 1)) == 0 && (N & (N - 1)) == 0) {
        float2* enc = (float2*)d_ws;
        ngp_encode<<<dim3(bpl * NLEV), dim3(256), 0, stream>>>(
            inputs, latent, table, enc, P, bplShift, nShift);
        ngp_mlp<<<dim3(P / 256), dim3(256), 0, stream>>>(
            enc, W1, b1, W2, b2, W3, b3, out, P);
    } else {
        ngp_fused<<<dim3(P / 256), dim3(256), 0, stream>>>(
            inputs, latent, table, W1, b1, W2, b2, W3, b3, out);
    }
}

// Round 6
// 235.210 us; speedup vs baseline: 13.9768x; 2.1525x over previous
//
#include <hip/hip_runtime.h>
#include <math.h>

// Color NGP, two-phase:
//   Phase A (encode): level-major grid; one thread per (point, level); 16 random
//     8B gathers per thread from one 4MB level slice -> L2-resident per XCD.
//     Writes enc as PACKED bf16 pairs (u32) [L][P] to workspace.
//   Phase B (MLP, MFMA): per block 256 points / 4 waves; per wave 64 points.
//     GEMM1 (K=32) -> GELU -> LDS (wave-private, XOR-swizzled) -> GEMM2 (K=64)
//     -> GELU -> LDS -> GEMM3 (M=16, 3 valid rows). mfma_f32_16x16x32_bf16.
//     C/D mapping: col = lane&15 (point), row = (lane>>4)*4 + reg (neuron).
//     A: lane&15 = M-row, k = (lane>>4)*8 + 2j + h (VGPR j holds k-pair, low=even).
//     B: lane&15 = N-col, same k mapping.
//   Round-5 lesson: scalar VALU MLP = 71K instr/thread, VALU-issue-bound 298us.
// Fallback: fused single-kernel VALU path if ws too small.

#define NLEV 16
#define TSIZE (1u << 19)
#define TMASK (TSIZE - 1u)

typedef __attribute__((ext_vector_type(8))) short bf16x8;
typedef __attribute__((ext_vector_type(4))) float f32x4;

union U32x4 { unsigned u[4]; uint4 q; bf16x8 v; };

// round-to-nearest-even f32 -> bf16 bits
__device__ __forceinline__ unsigned bfr(float x) {
    unsigned u = __float_as_uint(x);
    return (u + 0x7FFFu + ((u >> 16) & 1u)) >> 16;
}

// exact-GELU via A&S 7.1.26 erf (|eps| <= 1.5e-7)
__device__ __forceinline__ float gelu_fast(float x) {
    float ax = fabsf(x) * 0.70710678118654752440f;
    float t  = __builtin_amdgcn_rcpf(fmaf(0.3275911f, ax, 1.0f));
    float p  = t * (0.254829592f + t * (-0.284496736f + t * (1.421413741f +
               t * (-1.453152027f + t * 1.061405429f))));
    float e  = __expf(-ax * ax);
    float er = fmaf(-p, e, 1.0f);
    er = copysignf(er, x);
    return 0.5f * x * (1.0f + er);
}

__device__ __forceinline__ float gelu_exact(float x) {
    return 0.5f * x * (1.0f + erff(x * 0.70710678118654752440f));
}

// ---------------- Phase A: hash-grid encode, level-major ----------------
__global__ __launch_bounds__(256, 6) void ngp_encode(
    const float* __restrict__ inputs,   // [B,N,3]
    const float* __restrict__ latent,   // [B,1]
    const float* __restrict__ table,    // [16, 2^19, 2]
    unsigned* __restrict__ encb,        // [L][P] packed bf16 pair
    int P, int bplShift, int nShift)
{
    const int bid = blockIdx.x;
    const int l = bid >> bplShift;                  // level = slow dimension
    const int p = ((bid & ((1 << bplShift) - 1)) << 8) + threadIdx.x;

    float x0 = inputs[p * 3 + 0];
    float x1 = inputs[p * 3 + 1];
    float x2 = inputs[p * 3 + 2];
    float x3 = latent[p >> nShift];
    x0 = (x0 + 1.0f) * 0.5f;
    x1 = (x1 + 1.0f) * 0.5f;
    x2 = (x2 + 1.0f) * 0.5f;
    x3 = (x3 + 1.0f) * 0.5f;

    const float LOG2S = (float)log2(1.3819);        // matches np.float32(np.log2(1.3819))
    const float s = exp2f((float)l * LOG2S) * 16.0f - 1.0f;

    const float px = fmaf(x0, s, 0.5f);
    const float py = fmaf(x1, s, 0.5f);
    const float pz = fmaf(x2, s, 0.5f);
    const float pw = fmaf(x3, s, 0.5f);
    const float fx = floorf(px), fy = floorf(py), fz = floorf(pz), fw = floorf(pw);
    const float rx = px - fx, ry = py - fy, rz = pz - fz, rw = pw - fw;

    const unsigned a0 = (unsigned)(int)fx;               const unsigned a1 = a0 + 1u;
    const unsigned b0 = (unsigned)(int)fy * 2654435761u; const unsigned b1v = b0 + 2654435761u;
    const unsigned c0 = (unsigned)(int)fz * 805459861u;  const unsigned c1 = c0 + 805459861u;
    const unsigned d0 = (unsigned)(int)fw * 3674653429u; const unsigned d1 = d0 + 3674653429u;

    const float wx0 = 1.0f - rx, wy0 = 1.0f - ry, wz0 = 1.0f - rz, ww0 = 1.0f - rw;
    const float wxy[4] = { wx0 * wy0, rx * wy0, wx0 * ry, rx * ry };
    const float wzw[4] = { wz0 * ww0, rz * ww0, wz0 * rw, rz * rw };

    const float2* __restrict__ tab2 = (const float2*)table;
    const unsigned base = (unsigned)l * TSIZE;

    float acc0 = 0.0f, acc1 = 0.0f;
    #pragma unroll
    for (int c = 0; c < 16; ++c) {
        unsigned h = ((c & 1) ? a1 : a0) ^ ((c & 2) ? b1v : b0)
                   ^ ((c & 4) ? c1 : c0) ^ ((c & 8) ? d1 : d0);
        const float2 v = tab2[base + (h & TMASK)];
        const float wgt = wxy[c & 3] * wzw[c >> 2];
        acc0 = fmaf(wgt, v.x, acc0);
        acc1 = fmaf(wgt, v.y, acc1);
    }
    encb[l * P + p] = bfr(acc0) | (bfr(acc1) << 16);
}

// ---------------- Phase B: MFMA MLP 32->64->64->3 ----------------
__global__ __launch_bounds__(256) void ngp_mlp_mfma(
    const unsigned* __restrict__ encb,  // [L][P] packed bf16 pair
    const float* __restrict__ W1, const float* __restrict__ b1,   // [32,64],[64]
    const float* __restrict__ W2, const float* __restrict__ b2,   // [64,64],[64]
    const float* __restrict__ W3, const float* __restrict__ b3,   // [64,3],[3]
    float* __restrict__ out, int P)
{
    __shared__ __align__(16) unsigned char sH[4 * 8192];  // 4 waves x 64pt x 64n x bf16

    const int tid  = threadIdx.x;
    const int w    = tid >> 6;
    const int lane = tid & 63;
    const int lo16 = lane & 15;
    const int hi4  = lane >> 4;          // lane group 0..3
    const int pbase = blockIdx.x * 256 + w * 64;
    char* const myH = (char*)sH + w * 8192;

    // ---- A-fragments (bf16) for W1^T, W2^T, W3^T ----
    // A[m][k]: m = mt*16 + lo16 ; k = kc*32 + hi4*8 + 2j + h ; element = W[k][m]
    bf16x8 w1f[4];
    #pragma unroll
    for (int mt = 0; mt < 4; ++mt) {
        const int m = mt * 16 + lo16;
        const int kg = hi4 * 8;
        bf16x8 f;
        #pragma unroll
        for (int j = 0; j < 4; ++j) {
            f[2 * j    ] = (short)bfr(W1[(kg + 2 * j    ) * 64 + m]);
            f[2 * j + 1] = (short)bfr(W1[(kg + 2 * j + 1) * 64 + m]);
        }
        w1f[mt] = f;
    }
    bf16x8 w2f[4][2];
    #pragma unroll
    for (int mt = 0; mt < 4; ++mt) {
        const int m = mt * 16 + lo16;
        #pragma unroll
        for (int kc = 0; kc < 2; ++kc) {
            const int kg = kc * 32 + hi4 * 8;
            bf16x8 f;
            #pragma unroll
            for (int j = 0; j < 4; ++j) {
                f[2 * j    ] = (short)bfr(W2[(kg + 2 * j    ) * 64 + m]);
                f[2 * j + 1] = (short)bfr(W2[(kg + 2 * j + 1) * 64 + m]);
            }
            w2f[mt][kc] = f;
        }
    }
    bf16x8 w3f[2];
    {
        const int m = (lo16 < 3) ? lo16 : 2;   // clamp: rows 3..15 are ignored garbage
        #pragma unroll
        for (int kc = 0; kc < 2; ++kc) {
            const int kg = kc * 32 + hi4 * 8;
            bf16x8 f;
            #pragma unroll
            for (int j = 0; j < 4; ++j) {
                f[2 * j    ] = (short)bfr(W3[(kg + 2 * j    ) * 3 + m]);
                f[2 * j + 1] = (short)bfr(W3[(kg + 2 * j + 1) * 3 + m]);
            }
            w3f[kc] = f;
        }
    }

    const f32x4 zero = {0.0f, 0.0f, 0.0f, 0.0f};

    // ---- GEMM1: h1_pre[n][p] = W1^T @ enc^T ----
    f32x4 acc1[4][4];
    #pragma unroll
    for (int mt = 0; mt < 4; ++mt)
        #pragma unroll
        for (int nt = 0; nt < 4; ++nt) acc1[mt][nt] = zero;

    #pragma unroll
    for (int nt = 0; nt < 4; ++nt) {
        const int p = pbase + nt * 16 + lo16;
        const int lev0 = hi4 * 4;            // k = 2*lev + f
        U32x4 bu;
        #pragma unroll
        for (int j = 0; j < 4; ++j) bu.u[j] = encb[(lev0 + j) * P + p];
        #pragma unroll
        for (int mt = 0; mt < 4; ++mt)
            acc1[mt][nt] = __builtin_amdgcn_mfma_f32_16x16x32_bf16(
                w1f[mt], bu.v, acc1[mt][nt], 0, 0, 0);
    }

    // ---- epilogue 1: bias + GELU + pack -> LDS (swizzled) ----
    float4 b1v[4];
    #pragma unroll
    for (int mt = 0; mt < 4; ++mt)
        b1v[mt] = *(const float4*)(b1 + mt * 16 + hi4 * 4);

    #pragma unroll
    for (int mt = 0; mt < 4; ++mt) {
        const int nb  = mt * 16 + hi4 * 4;          // first neuron of the 4
        const int blkb = nb >> 3;
        #pragma unroll
        for (int nt = 0; nt < 4; ++nt) {
            const f32x4 a = acc1[mt][nt];
            const float h0 = gelu_fast(a[0] + b1v[mt].x);
            const float h1 = gelu_fast(a[1] + b1v[mt].y);
            const float h2 = gelu_fast(a[2] + b1v[mt].z);
            const float h3 = gelu_fast(a[3] + b1v[mt].w);
            const int pl = nt * 16 + lo16;
            char* dst = myH + pl * 128 + ((blkb ^ (pl & 7)) * 16) + ((nb & 7) * 2);
            *(uint2*)dst = make_uint2(bfr(h0) | (bfr(h1) << 16),
                                      bfr(h2) | (bfr(h3) << 16));
        }
    }

    // ---- GEMM2: h2_pre[n][p] = W2^T @ h1 ----
    f32x4 acc2[4][4];
    #pragma unroll
    for (int mt = 0; mt < 4; ++mt)
        #pragma unroll
        for (int nt = 0; nt < 4; ++nt) acc2[mt][nt] = zero;

    #pragma unroll
    for (int kc = 0; kc < 2; ++kc) {
        #pragma unroll
        for (int nt = 0; nt < 4; ++nt) {
            const int pl = nt * 16 + lo16;
            const int kb = kc * 4 + hi4;
            const char* src = myH + pl * 128 + ((kb ^ (pl & 7)) * 16);
            U32x4 bu; bu.q = *(const uint4*)src;
            #pragma unroll
            for (int mt = 0; mt < 4; ++mt)
                acc2[mt][nt] = __builtin_amdgcn_mfma_f32_16x16x32_bf16(
                    w2f[mt][kc], bu.v, acc2[mt][nt], 0, 0, 0);
        }
    }

    // ---- epilogue 2: bias + GELU + pack -> LDS (same region, same wave => in-order DS) ----
    float4 b2v[4];
    #pragma unroll
    for (int mt = 0; mt < 4; ++mt)
        b2v[mt] = *(const float4*)(b2 + mt * 16 + hi4 * 4);

    #pragma unroll
    for (int mt = 0; mt < 4; ++mt) {
        const int nb  = mt * 16 + hi4 * 4;
        const int blkb = nb >> 3;
        #pragma unroll
        for (int nt = 0; nt < 4; ++nt) {
            const f32x4 a = acc2[mt][nt];
            const float h0 = gelu_fast(a[0] + b2v[mt].x);
            const float h1 = gelu_fast(a[1] + b2v[mt].y);
            const float h2 = gelu_fast(a[2] + b2v[mt].z);
            const float h3 = gelu_fast(a[3] + b2v[mt].w);
            const int pl = nt * 16 + lo16;
            char* dst = myH + pl * 128 + ((blkb ^ (pl & 7)) * 16) + ((nb & 7) * 2);
            *(uint2*)dst = make_uint2(bfr(h0) | (bfr(h1) << 16),
                                      bfr(h2) | (bfr(h3) << 16));
        }
    }

    // ---- GEMM3: color[c][p] = W3^T @ h2 (rows 0..2 valid) ----
    f32x4 acc3[4];
    #pragma unroll
    for (int nt = 0; nt < 4; ++nt) acc3[nt] = zero;

    #pragma unroll
    for (int kc = 0; kc < 2; ++kc) {
        #pragma unroll
        for (int nt = 0; nt < 4; ++nt) {
            const int pl = nt * 16 + lo16;
            const int kb = kc * 4 + hi4;
            const char* src = myH + pl * 128 + ((kb ^ (pl & 7)) * 16);
            U32x4 bu; bu.q = *(const uint4*)src;
            acc3[nt] = __builtin_amdgcn_mfma_f32_16x16x32_bf16(
                w3f[kc], bu.v, acc3[nt], 0, 0, 0);
        }
    }

    const float b30 = b3[0], b31 = b3[1], b32 = b3[2];
    if (hi4 == 0) {   // rows 0..3 live in lane-group 0; regs 0..2 are colors
        #pragma unroll
        for (int nt = 0; nt < 4; ++nt) {
            const int p = pbase + nt * 16 + lo16;
            out[p * 3 + 0] = acc3[nt][0] + b30;
            out[p * 3 + 1] = acc3[nt][1] + b31;
            out[p * 3 + 2] = acc3[nt][2] + b32;
        }
    }
}

// ---------------- Fallback: fused single kernel (if ws too small) ----------------
__global__ __launch_bounds__(256) void ngp_fused(
    const float* __restrict__ inputs, const float* __restrict__ latent,
    const float* __restrict__ table,
    const float* __restrict__ W1, const float* __restrict__ b1,
    const float* __restrict__ W2, const float* __restrict__ b2,
    const float* __restrict__ W3, const float* __restrict__ b3,
    float* __restrict__ out)
{
    const int p = blockIdx.x * 256 + threadIdx.x;
    float x0 = inputs[p * 3 + 0];
    float x1 = inputs[p * 3 + 1];
    float x2 = inputs[p * 3 + 2];
    float x3 = latent[p >> 15];
    x0 = (x0 + 1.0f) * 0.5f; x1 = (x1 + 1.0f) * 0.5f;
    x2 = (x2 + 1.0f) * 0.5f; x3 = (x3 + 1.0f) * 0.5f;

    float h1[64];
    #pragma unroll
    for (int j = 0; j < 64; ++j) h1[j] = 0.0f;

    const float LOG2S = (float)log2(1.3819);
    const float2* __restrict__ tab2 = (const float2*)table;

    #pragma unroll 2
    for (int l = 0; l < NLEV; ++l) {
        const float s = exp2f((float)l * LOG2S) * 16.0f - 1.0f;
        const float px = fmaf(x0, s, 0.5f);
        const float py = fmaf(x1, s, 0.5f);
        const float pz = fmaf(x2, s, 0.5f);
        const float pw = fmaf(x3, s, 0.5f);
        const float fx = floorf(px), fy = floorf(py), fz = floorf(pz), fw = floorf(pw);
        const float rx = px - fx, ry = py - fy, rz = pz - fz, rw = pw - fw;
        const unsigned a0 = (unsigned)(int)fx;               const unsigned a1 = a0 + 1u;
        const unsigned b0 = (unsigned)(int)fy * 2654435761u; const unsigned b1v = b0 + 2654435761u;
        const unsigned c0 = (unsigned)(int)fz * 805459861u;  const unsigned c1 = c0 + 805459861u;
        const unsigned d0 = (unsigned)(int)fw * 3674653429u; const unsigned d1 = d0 + 3674653429u;
        const float wx0 = 1.0f - rx, wy0 = 1.0f - ry, wz0 = 1.0f - rz, ww0 = 1.0f - rw;
        const float wxy[4] = { wx0 * wy0, rx * wy0, wx0 * ry, rx * ry };
        const float wzw[4] = { wz0 * ww0, rz * ww0, wz0 * rw, rz * rw };
        const unsigned base = (unsigned)l * TSIZE;
        float acc0 = 0.0f, acc1 = 0.0f;
        #pragma unroll
        for (int c = 0; c < 16; ++c) {
            unsigned h = ((c & 1) ? a1 : a0) ^ ((c & 2) ? b1v : b0)
                       ^ ((c & 4) ? c1 : c0) ^ ((c & 8) ? d1 : d0);
            const float2 v = tab2[base + (h & TMASK)];
            const float wgt = wxy[c & 3] * wzw[c >> 2];
            acc0 = fmaf(wgt, v.x, acc0);
            acc1 = fmaf(wgt, v.y, acc1);
        }
        const float* __restrict__ w0 = W1 + (2 * l) * 64;
        const float* __restrict__ w1 = W1 + (2 * l + 1) * 64;
        #pragma unroll
        for (int j = 0; j < 64; ++j) {
            h1[j] = fmaf(acc0, w0[j], fmaf(acc1, w1[j], h1[j]));
        }
    }
    #pragma unroll
    for (int j = 0; j < 64; ++j) h1[j] = gelu_exact(h1[j] + b1[j]);

    float col0 = b3[0], col1 = b3[1], col2 = b3[2];
    #pragma unroll 1
    for (int ch = 0; ch < 8; ++ch) {
        float acc[8];
        #pragma unroll
        for (int k = 0; k < 8; ++k) acc[k] = b2[ch * 8 + k];
        #pragma unroll
        for (int i = 0; i < 64; ++i) {
            const float hv = h1[i];
            const float* __restrict__ wr = W2 + i * 64 + ch * 8;
            #pragma unroll
            for (int k = 0; k < 8; ++k) acc[k] = fmaf(hv, wr[k], acc[k]);
        }
        #pragma unroll
        for (int k = 0; k < 8; ++k) {
            const float g = gelu_exact(acc[k]);
            const int j2 = ch * 8 + k;
            col0 = fmaf(g, W3[j2 * 3 + 0], col0);
            col1 = fmaf(g, W3[j2 * 3 + 1], col1);
            col2 = fmaf(g, W3[j2 * 3 + 2], col2);
        }
    }
    out[p * 3 + 0] = col0;
    out[p * 3 + 1] = col1;
    out[p * 3 + 2] = col2;
}

extern "C" void kernel_launch(void* const* d_in, const int* in_sizes, int n_in,
                              void* d_out, int out_size, void* d_ws, size_t ws_size,
                              hipStream_t stream) {
    const float* inputs = (const float*)d_in[0];
    const float* latent = (const float*)d_in[1];
    const float* table  = (const float*)d_in[2];
    const float* W1 = (const float*)d_in[3];
    const float* b1 = (const float*)d_in[4];
    const float* W2 = (const float*)d_in[5];
    const float* b2 = (const float*)d_in[6];
    const float* W3 = (const float*)d_in[7];
    const float* b3 = (const float*)d_in[8];
    float* out = (float*)d_out;

    const int P = in_sizes[0] / 3;              // 262144
    const int B = in_sizes[1];                  // 8
    const int N = P / B;                        // 32768
    const int nShift = 31 - __builtin_clz(N);   // 15
    const int bpl = P / 256;                    // 1024 blocks per level
    const int bplShift = 31 - __builtin_clz(bpl);

    const size_t encBytes = (size_t)P * NLEV * sizeof(unsigned);  // 16.8 MB

    if (ws_size >= encBytes && (P & 255) == 0 && (bpl & (bpl - 1)) == 0 && (N & (N - 1)) == 0) {
        unsigned* encb = (unsigned*)d_ws;
        ngp_encode<<<dim3(bpl * NLEV), dim3(256), 0, stream>>>(
            inputs, latent, table, encb, P, bplShift, nShift);
        ngp_mlp_mfma<<<dim3(P / 256), dim3(256), 0, stream>>>(
            encb, W1, b1, W2, b2, W3, b3, out, P);
    } else {
        ngp_fused<<<dim3(P / 256), dim3(256), 0, stream>>>(
            inputs, latent, table, W1, b1, W2, b2, W3, b3, out);
    }
}